// Round 5
// baseline (561.936 us; speedup 1.0000x reference)
//
#include <hip/hip_runtime.h>

#define N_NODES 100000
#define N_EDGES 3200000
#define BATCH 16384
#define MAX_SLOTS 32768

// Node-degree histogram (round-4 structure, proven fast): 8 node partitions x
// 64 edge slices, packed 2x16-bit LDS counters.
#define HP 8
#define NPP 12500
#define WPP 6250
#define HG 64
#define EPS 50000
#define I4PS 12500
#define WP4 12500

// Bucket machinery: buckets over compacted slot space (128 slots each).
#define NBUCK 256
#define BSH 7            // slots per bucket = 128 = 1<<BSH
#define SLICES 256
#define EPS2 12500       // edges per slice
#define I4PS2 3125       // int4 loads per slice

// Workspace layout (byte offsets), peak 22,388,608 B (< proven 26.4 MB):
//   slot     @ 0         : 100000 ints (0 = unused, else slot_id+1)
//   counters @ 400000    : 16 ints ([0] = nSlots)
//   dinv     @ 400064    : 100000 floats
//   nodelist @ 800064    : 32768 ints
//   bstart   @ 931136    : 257 ints (bucket entry starts, exclusive prefix)
//   bpart    @ 932288    : 256x256 ints [bucket][slice] -> global positions
//   partials @ 1200000   : node-degree 16-bit partials, 12.8 MB (dead after k_dinv)
//   bins     @ 1200000   : OVERLAYS partials; packed entries (slot_local<<17|src)
//   emb      @ 14000000  : 32768 x 64 floats
#define OFF_SLOT     0
#define OFF_COUNTERS 400000
#define OFF_DINV     400064
#define OFF_NODELIST 800064
#define OFF_BSTART   931136
#define OFF_BPART    932288
#define OFF_PARTIALS 1200000
#define OFF_BINS     1200000
#define OFF_EMB      14000000

__global__ void k_init(int4* slot4, int* counters) {
    int i = blockIdx.x * blockDim.x + threadIdx.x;
    int stride = gridDim.x * blockDim.x;
    for (int j = i; j < 25000; j += stride) slot4[j] = make_int4(0, 0, 0, 0);
    if (i < 16) counters[i] = 0;
}

__global__ void k_flags(const int* __restrict__ pairs, int* __restrict__ slot) {
    int i = blockIdx.x * blockDim.x + threadIdx.x;
    if (i < 2 * BATCH) slot[pairs[i]] = 1;
}

// Wave-aggregated compaction: one atomic per wave.
__global__ void k_compact(int* __restrict__ slot, int* __restrict__ nodelist,
                          int* __restrict__ counters) {
    int n = blockIdx.x * blockDim.x + threadIdx.x;
    int lane = threadIdx.x & 63;
    int want = (n < N_NODES && slot[n]) ? 1 : 0;
    int incl = want;
#pragma unroll
    for (int d = 1; d < 64; d <<= 1) {
        int t = __shfl_up(incl, d, 64);
        if (lane >= d) incl += t;
    }
    int total = __shfl(incl, 63, 64);
    int base = 0;
    if (lane == 63 && total > 0) base = atomicAdd(&counters[0], total);
    base = __shfl(base, 63, 64);
    if (want) {
        int s = base + incl - 1;
        slot[n] = s + 1;
        nodelist[s] = n;
    }
}

__device__ __forceinline__ void hist1(int d, int base, unsigned* h) {
    int t = d - base;
    if ((unsigned)t < (unsigned)NPP) atomicAdd(&h[t >> 1], 1u << ((t & 1) << 4));
}

// Packed 16-bit LDS degree histogram over ALL nodes (dinv[src] needs every node).
__global__ void k_hist(const int* __restrict__ dst, unsigned* __restrict__ partials) {
    __shared__ unsigned h[WPP];
    int ps = blockIdx.x & 7, g = blockIdx.x >> 3;
    int base = ps * NPP;
    for (int i = threadIdx.x; i < WPP; i += 256) h[i] = 0;
    __syncthreads();
    const int4* d4 = (const int4*)(dst + g * EPS);
    for (int b0 = 0; b0 < 12288; b0 += 1024) {
        int4 a = d4[b0 + threadIdx.x];
        int4 b = d4[b0 + 256 + threadIdx.x];
        int4 c = d4[b0 + 512 + threadIdx.x];
        int4 e = d4[b0 + 768 + threadIdx.x];
        hist1(a.x, base, h); hist1(a.y, base, h); hist1(a.z, base, h); hist1(a.w, base, h);
        hist1(b.x, base, h); hist1(b.y, base, h); hist1(b.z, base, h); hist1(b.w, base, h);
        hist1(c.x, base, h); hist1(c.y, base, h); hist1(c.z, base, h); hist1(c.w, base, h);
        hist1(e.x, base, h); hist1(e.y, base, h); hist1(e.z, base, h); hist1(e.w, base, h);
    }
    {
        int i = 12288 + threadIdx.x;
        if (i < I4PS) {
            int4 a = d4[i];
            hist1(a.x, base, h); hist1(a.y, base, h); hist1(a.z, base, h); hist1(a.w, base, h);
        }
    }
    __syncthreads();
    unsigned* out = partials + (unsigned)((ps >> 1) * HG + g) * WP4 + (ps & 1) * WPP;
    for (int i = threadIdx.x; i < WPP; i += 256) out[i] = h[i];
}

// Reduce degree partials -> dinv (cnt array no longer needed).
__global__ void k_dinv(const unsigned* __restrict__ partials, float* __restrict__ dinv) {
    int id = blockIdx.x * blockDim.x + threadIdx.x;
    if (id >= 4 * WP4) return;
    int p4 = id / WP4, ww = id - p4 * WP4;
    const unsigned* q = partials + (unsigned)(p4 * HG) * WP4 + ww;
    unsigned run = 0;
#pragma unroll 8
    for (int g = 0; g < HG; ++g) run += q[(unsigned)g * WP4];
    int n0 = p4 * 25000 + 2 * ww;
    dinv[n0]     = rsqrtf((float)(run & 0xFFFFu) + 1.0f);
    dinv[n0 + 1] = rsqrtf((float)(run >> 16) + 1.0f);
}

// Single-pass bucket histogram: 256 LDS counters cover ALL buckets -> edges read once.
__global__ void k_bhist(const int* __restrict__ dst, const int* __restrict__ slot,
                        int* __restrict__ bpart) {
    __shared__ int lc[NBUCK];
    int g = blockIdx.x;
    if (threadIdx.x < NBUCK) lc[threadIdx.x] = 0;
    __syncthreads();
    const int4* d4 = (const int4*)(dst + g * EPS2);
    for (int i = threadIdx.x; i < I4PS2; i += 256) {
        int4 d = d4[i];
        int r;
        r = slot[d.x]; if (r) atomicAdd(&lc[(r - 1) >> BSH], 1);
        r = slot[d.y]; if (r) atomicAdd(&lc[(r - 1) >> BSH], 1);
        r = slot[d.z]; if (r) atomicAdd(&lc[(r - 1) >> BSH], 1);
        r = slot[d.w]; if (r) atomicAdd(&lc[(r - 1) >> BSH], 1);
    }
    __syncthreads();
    if (threadIdx.x < NBUCK) bpart[threadIdx.x * SLICES + g] = lc[threadIdx.x];
}

// Single block: per-bucket slice-prefix + cross-bucket scan. bpart becomes
// absolute write positions; bstart[b..b+1] bounds each bucket's entries.
__global__ void k_bpfx(int* __restrict__ bpart, int* __restrict__ bstart) {
    __shared__ int t[NBUCK];
    int b = threadIdx.x;
    int* row = bpart + b * SLICES;
    int total = 0;
    for (int g = 0; g < SLICES; ++g) total += row[g];
    t[b] = total;
    __syncthreads();
    for (int off = 1; off < NBUCK; off <<= 1) {
        int v = (b >= off) ? t[b - off] : 0;
        __syncthreads();
        t[b] += v;
        __syncthreads();
    }
    int excl = t[b] - total;
    bstart[b] = excl;
    if (b == NBUCK - 1) bstart[NBUCK] = t[b];
    int run = excl;
    for (int g = 0; g < SLICES; ++g) {
        int v = row[g];
        row[g] = run;
        run += v;
    }
}

__device__ __forceinline__ void scat1(int d, int s, const int* __restrict__ slot,
                                      int* cur, int* __restrict__ bins) {
    int r = slot[d];
    if (r) {
        int sl = r - 1;
        int pos = atomicAdd(&cur[sl >> BSH], 1);
        bins[pos] = ((sl & 127) << 17) | s;
    }
}

// Deterministic scatter: LDS cursors seeded from bpart; zero device atomics;
// writes are ~16-entry contiguous runs per (slice,bucket).
__global__ void k_bscatter(const int* __restrict__ src, const int* __restrict__ dst,
                           const int* __restrict__ slot, const int* __restrict__ bpart,
                           int* __restrict__ bins) {
    __shared__ int cur[NBUCK];
    int g = blockIdx.x;
    if (threadIdx.x < NBUCK) cur[threadIdx.x] = bpart[threadIdx.x * SLICES + g];
    __syncthreads();
    const int4* d4 = (const int4*)(dst + g * EPS2);
    const int4* s4 = (const int4*)(src + g * EPS2);
    for (int i = threadIdx.x; i < I4PS2; i += 256) {
        int4 d = d4[i];
        int4 s = s4[i];
        scat1(d.x, s.x, slot, cur, bins);
        scat1(d.y, s.y, slot, cur, bins);
        scat1(d.z, s.z, slot, cur, bins);
        scat1(d.w, s.w, slot, cur, bins);
    }
}

// One block per bucket: 128 slots x 64 dims accumulated in LDS (ds_add_f32).
// Wave processes 8 entries/iter for ILP on the L3-resident w-row gathers.
__global__ void k_bgather(const int* __restrict__ bstart, const int* __restrict__ bins,
                          const int* __restrict__ nodelist, const float* __restrict__ w,
                          const float* __restrict__ dinv, const float* __restrict__ bias,
                          const int* __restrict__ counters, float* __restrict__ emb) {
    __shared__ float acc[128 * 64];
    int b = blockIdx.x;
    int tid = threadIdx.x;
    int wave = tid >> 6, lane = tid & 63;
    for (int i = tid; i < 128 * 64; i += 256) acc[i] = 0.f;
    __syncthreads();
    int beg = bstart[b], end = bstart[b + 1];
    int C = (end - beg) >> 3;
    for (int c = wave; c < C; c += 4) {
        int j = beg + (c << 3);
        int e0 = bins[j],     e1 = bins[j + 1], e2 = bins[j + 2], e3 = bins[j + 3];
        int e4 = bins[j + 4], e5 = bins[j + 5], e6 = bins[j + 6], e7 = bins[j + 7];
        int s0 = e0 & 0x1FFFF, s1 = e1 & 0x1FFFF, s2 = e2 & 0x1FFFF, s3 = e3 & 0x1FFFF;
        int s4 = e4 & 0x1FFFF, s5 = e5 & 0x1FFFF, s6 = e6 & 0x1FFFF, s7 = e7 & 0x1FFFF;
        float v0 = w[(s0 << 6) + lane] * dinv[s0];
        float v1 = w[(s1 << 6) + lane] * dinv[s1];
        float v2 = w[(s2 << 6) + lane] * dinv[s2];
        float v3 = w[(s3 << 6) + lane] * dinv[s3];
        float v4 = w[(s4 << 6) + lane] * dinv[s4];
        float v5 = w[(s5 << 6) + lane] * dinv[s5];
        float v6 = w[(s6 << 6) + lane] * dinv[s6];
        float v7 = w[(s7 << 6) + lane] * dinv[s7];
        atomicAdd(&acc[((e0 >> 17) << 6) + lane], v0);
        atomicAdd(&acc[((e1 >> 17) << 6) + lane], v1);
        atomicAdd(&acc[((e2 >> 17) << 6) + lane], v2);
        atomicAdd(&acc[((e3 >> 17) << 6) + lane], v3);
        atomicAdd(&acc[((e4 >> 17) << 6) + lane], v4);
        atomicAdd(&acc[((e5 >> 17) << 6) + lane], v5);
        atomicAdd(&acc[((e6 >> 17) << 6) + lane], v6);
        atomicAdd(&acc[((e7 >> 17) << 6) + lane], v7);
    }
    if (wave == 0) {
        for (int j = beg + (C << 3); j < end; ++j) {
            int e = bins[j];
            int s = e & 0x1FFFF;
            atomicAdd(&acc[((e >> 17) << 6) + lane], w[(s << 6) + lane] * dinv[s]);
        }
    }
    __syncthreads();
    int nS = counters[0];
    float bi = bias[lane];
    for (int s0 = wave; s0 < 128; s0 += 4) {
        int gs = (b << BSH) + s0;
        if (gs < nS) {
            int n = nodelist[gs];
            float dn = dinv[n];
            emb[(gs << 6) + lane] =
                acc[(s0 << 6) + lane] * dn + w[(n << 6) + lane] * (dn * dn) + bi;
        }
    }
}

// One wave per pair: FM pairwise term == dot(emb_a, emb_b).
__global__ void k_final(const int* __restrict__ pairs, const int* __restrict__ slot,
                        const float* __restrict__ emb, const float* __restrict__ lw,
                        const float* __restrict__ lb, float* __restrict__ out) {
    int p = (blockIdx.x * blockDim.x + threadIdx.x) >> 6;
    int lane = threadIdx.x & 63;
    if (p >= BATCH) return;
    int a = pairs[p * 2 + 0];
    int b = pairs[p * 2 + 1];
    int sa = slot[a] - 1;
    int sb = slot[b] - 1;
    float ea = emb[(sa << 6) + lane];
    float eb = emb[(sb << 6) + lane];
    float prod = ea * eb;
#pragma unroll
    for (int m = 32; m >= 1; m >>= 1) prod += __shfl_xor(prod, m, 64);
    if (lane == 0) out[p] = lw[a] + lw[b] + lb[0] + prod;
}

extern "C" void kernel_launch(void* const* d_in, const int* in_sizes, int n_in,
                              void* d_out, int out_size, void* d_ws, size_t ws_size,
                              hipStream_t stream) {
    const float* gcn_weight    = (const float*)d_in[0];
    const float* gcn_bias      = (const float*)d_in[1];
    const float* linear_weight = (const float*)d_in[2];
    const float* linear_bias   = (const float*)d_in[3];
    const int*   edge_index    = (const int*)d_in[4];
    const int*   pairs         = (const int*)d_in[5];
    float* out = (float*)d_out;

    char* ws = (char*)d_ws;
    int*      slot     = (int*)     (ws + OFF_SLOT);
    int*      counters = (int*)     (ws + OFF_COUNTERS);
    float*    dinv     = (float*)   (ws + OFF_DINV);
    int*      nodelist = (int*)     (ws + OFF_NODELIST);
    int*      bstart   = (int*)     (ws + OFF_BSTART);
    int*      bpart    = (int*)     (ws + OFF_BPART);
    unsigned* partials = (unsigned*)(ws + OFF_PARTIALS);
    int*      bins     = (int*)     (ws + OFF_BINS);
    float*    emb      = (float*)   (ws + OFF_EMB);

    const int* src_arr = edge_index;
    const int* dst_arr = edge_index + N_EDGES;

    k_init<<<98, 256, 0, stream>>>((int4*)(ws + OFF_SLOT), counters);
    k_flags<<<128, 256, 0, stream>>>(pairs, slot);
    k_compact<<<391, 256, 0, stream>>>(slot, nodelist, counters);
    k_hist<<<HP * HG, 256, 0, stream>>>(dst_arr, partials);
    k_dinv<<<196, 256, 0, stream>>>(partials, dinv);      // partials dead after this
    k_bhist<<<SLICES, 256, 0, stream>>>(dst_arr, slot, bpart);
    k_bpfx<<<1, 256, 0, stream>>>(bpart, bstart);
    k_bscatter<<<SLICES, 256, 0, stream>>>(src_arr, dst_arr, slot, bpart, bins);
    k_bgather<<<NBUCK, 256, 0, stream>>>(bstart, bins, nodelist, gcn_weight, dinv,
                                         gcn_bias, counters, emb);
    k_final<<<BATCH / 4, 256, 0, stream>>>(pairs, slot, emb, linear_weight, linear_bias, out);
}

// Round 6
// 251.471 us; speedup vs baseline: 2.2346x; 2.2346x over previous
//
#include <hip/hip_runtime.h>

#define N_NODES 100000
#define N_EDGES 3200000
#define BATCH 16384
#define MAX_SLOTS 32768

// Node-degree histogram: 8 node partitions x 64 edge slices, packed 2x16-bit.
#define HP 8
#define NPP 12500
#define WPP 6250
#define HG 64
#define EPS 50000
#define I4PS 12500
#define WP4 12500

// Bucket machinery over compacted slot space (128 slots / bucket).
#define NBUCK 256
#define BSH 7
#define SLICES 256
#define EPS2 12500
#define I4PS2 3125

// Workspace layout (byte offsets), peak 19,714,176 B (< proven 26.4 MB):
//   slot      @ 0        : 100000 ints (0 = unused, else slot_id+1)
//   counters  @ 400000   : 16 ints ([0] = nSlots)
//   dinv      @ 400064   : 100000 floats
//   nodelist  @ 800064   : 32768 ints
//   bstart    @ 931136   : 257 ints
//   bpart     @ 932288   : 256x256 ints [bucket][slice]
//   slotstart @ 1194432  : 32769 ints (per-slot CSR starts)
//   partials  @ 1325568  : 12.8 MB degree partials (dead after k_dinv)
//   bins      @ 1325568  : OVERLAYS partials; packed (slot_local<<17 | src), cap 1.2M
//   bins2     @ 6525568  : slot-sorted src ids, cap 1.2M
//   emb       @ 11325568 : 32768 x 64 floats
#define OFF_SLOT      0
#define OFF_COUNTERS  400000
#define OFF_DINV      400064
#define OFF_NODELIST  800064
#define OFF_BSTART    931136
#define OFF_BPART     932288
#define OFF_SLOTSTART 1194432
#define OFF_PARTIALS  1325568
#define OFF_BINS      1325568
#define OFF_BINS2     6525568
#define OFF_EMB       11325568

__global__ void k_init(int4* slot4, int* counters) {
    int i = blockIdx.x * blockDim.x + threadIdx.x;
    int stride = gridDim.x * blockDim.x;
    for (int j = i; j < 25000; j += stride) slot4[j] = make_int4(0, 0, 0, 0);
    if (i < 16) counters[i] = 0;
}

__global__ void k_flags(const int* __restrict__ pairs, int* __restrict__ slot) {
    int i = blockIdx.x * blockDim.x + threadIdx.x;
    if (i < 2 * BATCH) slot[pairs[i]] = 1;
}

// Wave-aggregated compaction: one atomic per wave.
__global__ void k_compact(int* __restrict__ slot, int* __restrict__ nodelist,
                          int* __restrict__ counters) {
    int n = blockIdx.x * blockDim.x + threadIdx.x;
    int lane = threadIdx.x & 63;
    int want = (n < N_NODES && slot[n]) ? 1 : 0;
    int incl = want;
#pragma unroll
    for (int d = 1; d < 64; d <<= 1) {
        int t = __shfl_up(incl, d, 64);
        if (lane >= d) incl += t;
    }
    int total = __shfl(incl, 63, 64);
    int base = 0;
    if (lane == 63 && total > 0) base = atomicAdd(&counters[0], total);
    base = __shfl(base, 63, 64);
    if (want) {
        int s = base + incl - 1;
        slot[n] = s + 1;
        nodelist[s] = n;
    }
}

__device__ __forceinline__ void hist1(int d, int base, unsigned* h) {
    int t = d - base;
    if ((unsigned)t < (unsigned)NPP) atomicAdd(&h[t >> 1], 1u << ((t & 1) << 4));
}

// Packed 16-bit LDS degree histogram over ALL nodes.
__global__ void k_hist(const int* __restrict__ dst, unsigned* __restrict__ partials) {
    __shared__ unsigned h[WPP];
    int ps = blockIdx.x & 7, g = blockIdx.x >> 3;
    int base = ps * NPP;
    for (int i = threadIdx.x; i < WPP; i += 256) h[i] = 0;
    __syncthreads();
    const int4* d4 = (const int4*)(dst + g * EPS);
    for (int b0 = 0; b0 < 12288; b0 += 1024) {
        int4 a = d4[b0 + threadIdx.x];
        int4 b = d4[b0 + 256 + threadIdx.x];
        int4 c = d4[b0 + 512 + threadIdx.x];
        int4 e = d4[b0 + 768 + threadIdx.x];
        hist1(a.x, base, h); hist1(a.y, base, h); hist1(a.z, base, h); hist1(a.w, base, h);
        hist1(b.x, base, h); hist1(b.y, base, h); hist1(b.z, base, h); hist1(b.w, base, h);
        hist1(c.x, base, h); hist1(c.y, base, h); hist1(c.z, base, h); hist1(c.w, base, h);
        hist1(e.x, base, h); hist1(e.y, base, h); hist1(e.z, base, h); hist1(e.w, base, h);
    }
    {
        int i = 12288 + threadIdx.x;
        if (i < I4PS) {
            int4 a = d4[i];
            hist1(a.x, base, h); hist1(a.y, base, h); hist1(a.z, base, h); hist1(a.w, base, h);
        }
    }
    __syncthreads();
    unsigned* out = partials + (unsigned)((ps >> 1) * HG + g) * WP4 + (ps & 1) * WPP;
    for (int i = threadIdx.x; i < WPP; i += 256) out[i] = h[i];
}

// Reduce degree partials -> dinv.
__global__ void k_dinv(const unsigned* __restrict__ partials, float* __restrict__ dinv) {
    int id = blockIdx.x * blockDim.x + threadIdx.x;
    if (id >= 4 * WP4) return;
    int p4 = id / WP4, ww = id - p4 * WP4;
    const unsigned* q = partials + (unsigned)(p4 * HG) * WP4 + ww;
    unsigned run = 0;
#pragma unroll 8
    for (int g = 0; g < HG; ++g) run += q[(unsigned)g * WP4];
    int n0 = p4 * 25000 + 2 * ww;
    dinv[n0]     = rsqrtf((float)(run & 0xFFFFu) + 1.0f);
    dinv[n0 + 1] = rsqrtf((float)(run >> 16) + 1.0f);
}

// Single-pass bucket histogram: 256 LDS counters, edges read once.
__global__ void k_bhist(const int* __restrict__ dst, const int* __restrict__ slot,
                        int* __restrict__ bpart) {
    __shared__ int lc[NBUCK];
    int g = blockIdx.x;
    if (threadIdx.x < NBUCK) lc[threadIdx.x] = 0;
    __syncthreads();
    const int4* d4 = (const int4*)(dst + g * EPS2);
    for (int i = threadIdx.x; i < I4PS2; i += 256) {
        int4 d = d4[i];
        int r;
        r = slot[d.x]; if (r) atomicAdd(&lc[(r - 1) >> BSH], 1);
        r = slot[d.y]; if (r) atomicAdd(&lc[(r - 1) >> BSH], 1);
        r = slot[d.z]; if (r) atomicAdd(&lc[(r - 1) >> BSH], 1);
        r = slot[d.w]; if (r) atomicAdd(&lc[(r - 1) >> BSH], 1);
    }
    __syncthreads();
    if (threadIdx.x < NBUCK) bpart[threadIdx.x * SLICES + g] = lc[threadIdx.x];
}

// Single block: per-bucket slice-prefix + cross-bucket scan.
__global__ void k_bpfx(int* __restrict__ bpart, int* __restrict__ bstart,
                       int* __restrict__ slotstart) {
    __shared__ int t[NBUCK];
    int b = threadIdx.x;
    int* row = bpart + b * SLICES;
    int total = 0;
    for (int g = 0; g < SLICES; ++g) total += row[g];
    t[b] = total;
    __syncthreads();
    for (int off = 1; off < NBUCK; off <<= 1) {
        int v = (b >= off) ? t[b - off] : 0;
        __syncthreads();
        t[b] += v;
        __syncthreads();
    }
    int excl = t[b] - total;
    bstart[b] = excl;
    if (b == NBUCK - 1) {
        bstart[NBUCK] = t[b];
        slotstart[MAX_SLOTS] = t[b];
    }
    int run = excl;
    for (int g = 0; g < SLICES; ++g) {
        int v = row[g];
        row[g] = run;
        run += v;
    }
}

__device__ __forceinline__ void scat1(int d, int s, const int* __restrict__ slot,
                                      int* cur, int* __restrict__ bins) {
    int r = slot[d];
    if (r) {
        int sl = r - 1;
        int pos = atomicAdd(&cur[sl >> BSH], 1);
        bins[pos] = ((sl & 127) << 17) | s;
    }
}

// Deterministic bucket scatter: LDS cursors only, zero device atomics.
__global__ void k_bscatter(const int* __restrict__ src, const int* __restrict__ dst,
                           const int* __restrict__ slot, const int* __restrict__ bpart,
                           int* __restrict__ bins) {
    __shared__ int cur[NBUCK];
    int g = blockIdx.x;
    if (threadIdx.x < NBUCK) cur[threadIdx.x] = bpart[threadIdx.x * SLICES + g];
    __syncthreads();
    const int4* d4 = (const int4*)(dst + g * EPS2);
    const int4* s4 = (const int4*)(src + g * EPS2);
    for (int i = threadIdx.x; i < I4PS2; i += 256) {
        int4 d = d4[i];
        int4 s = s4[i];
        scat1(d.x, s.x, slot, cur, bins);
        scat1(d.y, s.y, slot, cur, bins);
        scat1(d.z, s.z, slot, cur, bins);
        scat1(d.w, s.w, slot, cur, bins);
    }
}

// Per-bucket counting sort -> full per-slot CSR (slotstart, bins2). LDS atomics only.
__global__ void k_bsort(const int* __restrict__ bstart, const int* __restrict__ bins,
                        int* __restrict__ slotstart, int* __restrict__ bins2) {
    __shared__ int lc[128];
    __shared__ int st[128];
    int b = blockIdx.x;
    int tid = threadIdx.x;
    if (tid < 128) lc[tid] = 0;
    __syncthreads();
    int beg = bstart[b], end = bstart[b + 1];
    for (int j = beg + tid; j < end; j += 256)
        atomicAdd(&lc[(bins[j] >> 17) & 127], 1);
    __syncthreads();
    if (tid < 128) st[tid] = lc[tid];
    __syncthreads();
    for (int off = 1; off < 128; off <<= 1) {
        int v = (tid < 128 && tid >= off) ? st[tid - off] : 0;
        __syncthreads();
        if (tid < 128) st[tid] += v;
        __syncthreads();
    }
    if (tid < 128) {
        int s0 = beg + st[tid] - lc[tid];   // exclusive prefix
        slotstart[(b << 7) + tid] = s0;
        lc[tid] = s0;                        // reuse as cursor
    }
    __syncthreads();
    for (int j = beg + tid; j < end; j += 256) {
        int e = bins[j];
        int pos = atomicAdd(&lc[(e >> 17) & 127], 1);
        bins2[pos] = e & 0x1FFFF;
    }
}

// One wave per slot, lane = dim, register accumulation (round-3 proven).
__global__ void k_gather(const int* __restrict__ nodelist, const int* __restrict__ slotstart,
                         const int* __restrict__ bins2, const float* __restrict__ w,
                         const float* __restrict__ dinv, const float* __restrict__ bias,
                         const int* __restrict__ counters, float* __restrict__ emb) {
    int s = (blockIdx.x * blockDim.x + threadIdx.x) >> 6;
    int lane = threadIdx.x & 63;
    if (s >= counters[0]) return;
    int n = nodelist[s];
    int beg = slotstart[s];
    int end = slotstart[s + 1];
    float acc = 0.f;
    int j = beg;
    for (; j + 4 <= end; j += 4) {
        int s0 = bins2[j], s1 = bins2[j + 1], s2 = bins2[j + 2], s3 = bins2[j + 3];
        float d0 = dinv[s0], d1 = dinv[s1], d2 = dinv[s2], d3 = dinv[s3];
        acc += w[(s0 << 6) + lane] * d0;
        acc += w[(s1 << 6) + lane] * d1;
        acc += w[(s2 << 6) + lane] * d2;
        acc += w[(s3 << 6) + lane] * d3;
    }
    for (; j < end; ++j) {
        int si = bins2[j];
        acc += w[(si << 6) + lane] * dinv[si];
    }
    float dn = dinv[n];
    emb[(s << 6) + lane] = acc * dn + w[(n << 6) + lane] * (dn * dn) + bias[lane];
}

// One wave per pair: FM pairwise term == dot(emb_a, emb_b).
__global__ void k_final(const int* __restrict__ pairs, const int* __restrict__ slot,
                        const float* __restrict__ emb, const float* __restrict__ lw,
                        const float* __restrict__ lb, float* __restrict__ out) {
    int p = (blockIdx.x * blockDim.x + threadIdx.x) >> 6;
    int lane = threadIdx.x & 63;
    if (p >= BATCH) return;
    int a = pairs[p * 2 + 0];
    int b = pairs[p * 2 + 1];
    int sa = slot[a] - 1;
    int sb = slot[b] - 1;
    float ea = emb[(sa << 6) + lane];
    float eb = emb[(sb << 6) + lane];
    float prod = ea * eb;
#pragma unroll
    for (int m = 32; m >= 1; m >>= 1) prod += __shfl_xor(prod, m, 64);
    if (lane == 0) out[p] = lw[a] + lw[b] + lb[0] + prod;
}

extern "C" void kernel_launch(void* const* d_in, const int* in_sizes, int n_in,
                              void* d_out, int out_size, void* d_ws, size_t ws_size,
                              hipStream_t stream) {
    const float* gcn_weight    = (const float*)d_in[0];
    const float* gcn_bias      = (const float*)d_in[1];
    const float* linear_weight = (const float*)d_in[2];
    const float* linear_bias   = (const float*)d_in[3];
    const int*   edge_index    = (const int*)d_in[4];
    const int*   pairs         = (const int*)d_in[5];
    float* out = (float*)d_out;

    char* ws = (char*)d_ws;
    int*      slot      = (int*)     (ws + OFF_SLOT);
    int*      counters  = (int*)     (ws + OFF_COUNTERS);
    float*    dinv      = (float*)   (ws + OFF_DINV);
    int*      nodelist  = (int*)     (ws + OFF_NODELIST);
    int*      bstart    = (int*)     (ws + OFF_BSTART);
    int*      bpart     = (int*)     (ws + OFF_BPART);
    int*      slotstart = (int*)     (ws + OFF_SLOTSTART);
    unsigned* partials  = (unsigned*)(ws + OFF_PARTIALS);
    int*      bins      = (int*)     (ws + OFF_BINS);
    int*      bins2     = (int*)     (ws + OFF_BINS2);
    float*    emb       = (float*)   (ws + OFF_EMB);

    const int* src_arr = edge_index;
    const int* dst_arr = edge_index + N_EDGES;

    k_init<<<98, 256, 0, stream>>>((int4*)(ws + OFF_SLOT), counters);
    k_flags<<<128, 256, 0, stream>>>(pairs, slot);
    k_compact<<<391, 256, 0, stream>>>(slot, nodelist, counters);
    k_hist<<<HP * HG, 256, 0, stream>>>(dst_arr, partials);
    k_dinv<<<196, 256, 0, stream>>>(partials, dinv);      // partials dead after this
    k_bhist<<<SLICES, 256, 0, stream>>>(dst_arr, slot, bpart);
    k_bpfx<<<1, 256, 0, stream>>>(bpart, bstart, slotstart);
    k_bscatter<<<SLICES, 256, 0, stream>>>(src_arr, dst_arr, slot, bpart, bins);
    k_bsort<<<NBUCK, 256, 0, stream>>>(bstart, bins, slotstart, bins2);
    k_gather<<<MAX_SLOTS / 4, 256, 0, stream>>>(nodelist, slotstart, bins2, gcn_weight,
                                                dinv, gcn_bias, counters, emb);
    k_final<<<BATCH / 4, 256, 0, stream>>>(pairs, slot, emb, linear_weight, linear_bias, out);
}

// Round 7
// 218.208 us; speedup vs baseline: 2.5752x; 1.1524x over previous
//
#include <hip/hip_runtime.h>

#define N_NODES 100000
#define N_EDGES 3200000
#define BATCH 16384
#define MAX_SLOTS 32768

// Degree histogram: 4 node partitions x 50KB LDS x 64 edge slices.
#define HP 4
#define NPP 25000
#define WPP 12500
#define HG 64
#define EPS 50000
#define I4PS 12500

// Bucket machinery over compacted slot space (128 slots / bucket).
#define NBUCK 256
#define BSH 7
#define SLICES 256
#define EPS2 12500
#define I4PS2 3125

// Workspace layout (byte offsets), peak 22,526,592 B (< proven 26.4 MB):
//   slot      @ 0         : 100000 ints
//   counters  @ 400000    : 16 ints ([0] = nSlots)
//   dinv      @ 400064    : 100000 floats
//   nodelist  @ 800064    : 32768 ints
//   bstart    @ 931136    : 257 ints
//   btot      @ 932224    : 256 ints
//   bpart     @ 933248    : 256x256 ints [bucket][slice]
//   slotstart @ 1195392   : 32769 ints
//   partials  @ 1326592   : 12.8 MB (dead after k_dinv)
//   wh        @ 1326592   : OVERLAYS partials; bf16 w*dinv, 100000x64x2 B
//   bins2     @ 14126592  : slot-sorted src ids, cap 1.05M ints
//   bins      @ 18326592  : packed (slot_local<<17|src), cap 1.05M (dead after bsort)
//   emb       @ 18326592  : OVERLAYS bins; bf16 32768x64
#define OFF_SLOT      0
#define OFF_COUNTERS  400000
#define OFF_DINV      400064
#define OFF_NODELIST  800064
#define OFF_BSTART    931136
#define OFF_BTOT      932224
#define OFF_BPART     933248
#define OFF_SLOTSTART 1195392
#define OFF_PARTIALS  1326592
#define OFF_WH        1326592
#define OFF_BINS2     14126592
#define OFF_BINS      18326592
#define OFF_EMB       18326592

__device__ __forceinline__ unsigned bfr(float f) {   // fp32 -> bf16 bits, RNE
    unsigned u = __float_as_uint(f);
    return (u + 0x7FFFu + ((u >> 16) & 1u)) >> 16;
}
__device__ __forceinline__ float bfx(unsigned h) {   // bf16 bits -> fp32
    return __uint_as_float(h << 16);
}

__global__ void k_init(int4* slot4, int* counters) {
    int i = blockIdx.x * blockDim.x + threadIdx.x;
    int stride = gridDim.x * blockDim.x;
    for (int j = i; j < 25000; j += stride) slot4[j] = make_int4(0, 0, 0, 0);
    if (i < 16) counters[i] = 0;
}

__global__ void k_flags(const int* __restrict__ pairs, int* __restrict__ slot) {
    int i = blockIdx.x * blockDim.x + threadIdx.x;
    if (i < 2 * BATCH) slot[pairs[i]] = 1;
}

// Wave-aggregated compaction: one atomic per wave.
__global__ void k_compact(int* __restrict__ slot, int* __restrict__ nodelist,
                          int* __restrict__ counters) {
    int n = blockIdx.x * blockDim.x + threadIdx.x;
    int lane = threadIdx.x & 63;
    int want = (n < N_NODES && slot[n]) ? 1 : 0;
    int incl = want;
#pragma unroll
    for (int d = 1; d < 64; d <<= 1) {
        int t = __shfl_up(incl, d, 64);
        if (lane >= d) incl += t;
    }
    int total = __shfl(incl, 63, 64);
    int base = 0;
    if (lane == 63 && total > 0) base = atomicAdd(&counters[0], total);
    base = __shfl(base, 63, 64);
    if (want) {
        int s = base + incl - 1;
        slot[n] = s + 1;
        nodelist[s] = n;
    }
}

__device__ __forceinline__ void hist1(int d, int base, unsigned* h) {
    int t = d - base;
    if ((unsigned)t < (unsigned)NPP) atomicAdd(&h[t >> 1], 1u << ((t & 1) << 4));
}

// Packed 16-bit LDS degree histogram: 4 partitions (50KB LDS), 512 threads.
__global__ void k_hist(const int* __restrict__ dst, unsigned* __restrict__ partials) {
    __shared__ unsigned h[WPP];
    int ps = blockIdx.x & 3, g = blockIdx.x >> 2;
    int base = ps * NPP;
    for (int i = threadIdx.x; i < WPP; i += 512) h[i] = 0;
    __syncthreads();
    const int4* d4 = (const int4*)(dst + g * EPS);
    for (int i = threadIdx.x; i < 12288; i += 1024) {
        int4 a = d4[i];
        int4 b = d4[i + 512];
        hist1(a.x, base, h); hist1(a.y, base, h); hist1(a.z, base, h); hist1(a.w, base, h);
        hist1(b.x, base, h); hist1(b.y, base, h); hist1(b.z, base, h); hist1(b.w, base, h);
    }
    {
        int i = 12288 + threadIdx.x;
        if (i < I4PS) {
            int4 a = d4[i];
            hist1(a.x, base, h); hist1(a.y, base, h); hist1(a.z, base, h); hist1(a.w, base, h);
        }
    }
    __syncthreads();
    unsigned* out = partials + (unsigned)(ps * HG + g) * WPP;
    for (int i = threadIdx.x; i < WPP; i += 512) out[i] = h[i];
}

// Reduce degree partials -> dinv.
__global__ void k_dinv(const unsigned* __restrict__ partials, float* __restrict__ dinv) {
    int id = blockIdx.x * blockDim.x + threadIdx.x;
    if (id >= HP * WPP) return;
    int p = id / WPP, ww = id - p * WPP;
    const unsigned* q = partials + (unsigned)(p * HG) * WPP + ww;
    unsigned run = 0;
#pragma unroll 8
    for (int g = 0; g < HG; ++g) run += q[(unsigned)g * WPP];
    int n0 = p * NPP + 2 * ww;
    dinv[n0]     = rsqrtf((float)(run & 0xFFFFu) + 1.0f);
    dinv[n0 + 1] = rsqrtf((float)(run >> 16) + 1.0f);
}

// wh[n][d] = bf16(w[n][d] * dinv[n]); packed 2 per uint.
__global__ void k_cvt(const float2* __restrict__ w2, const float* __restrict__ dinv,
                      unsigned* __restrict__ wh) {
    int i = blockIdx.x * 256 + threadIdx.x;
    if (i >= N_NODES * 32) return;
    float d = dinv[i >> 5];
    float2 v = w2[i];
    wh[i] = bfr(v.x * d) | (bfr(v.y * d) << 16);
}

// Single-pass bucket histogram: 256 LDS counters, edges read once.
__global__ void k_bhist(const int* __restrict__ dst, const int* __restrict__ slot,
                        int* __restrict__ bpart) {
    __shared__ int lc[NBUCK];
    int g = blockIdx.x;
    if (threadIdx.x < NBUCK) lc[threadIdx.x] = 0;
    __syncthreads();
    const int4* d4 = (const int4*)(dst + g * EPS2);
    for (int i = threadIdx.x; i < I4PS2; i += 512) {
        int4 d = d4[i];
        int r;
        r = slot[d.x]; if (r) atomicAdd(&lc[(r - 1) >> BSH], 1);
        r = slot[d.y]; if (r) atomicAdd(&lc[(r - 1) >> BSH], 1);
        r = slot[d.z]; if (r) atomicAdd(&lc[(r - 1) >> BSH], 1);
        r = slot[d.w]; if (r) atomicAdd(&lc[(r - 1) >> BSH], 1);
    }
    __syncthreads();
    if (threadIdx.x < NBUCK) bpart[threadIdx.x * SLICES + g] = lc[threadIdx.x];
}

// Per-bucket slice scan (parallel): bpart row -> exclusive prefix (no base); total -> btot.
__global__ void k_bpfx1(int* __restrict__ bpart, int* __restrict__ btot) {
    __shared__ int t[SLICES];
    int b = blockIdx.x, g = threadIdx.x;
    int v = bpart[b * SLICES + g];
    t[g] = v;
    __syncthreads();
    for (int off = 1; off < SLICES; off <<= 1) {
        int x = (g >= off) ? t[g - off] : 0;
        __syncthreads();
        t[g] += x;
        __syncthreads();
    }
    bpart[b * SLICES + g] = t[g] - v;
    if (g == SLICES - 1) btot[b] = t[g];
}

// Cross-bucket scan of totals -> bstart.
__global__ void k_bpfx2(const int* __restrict__ btot, int* __restrict__ bstart,
                        int* __restrict__ slotstart) {
    __shared__ int t[NBUCK];
    int b = threadIdx.x;
    int v = btot[b];
    t[b] = v;
    __syncthreads();
    for (int off = 1; off < NBUCK; off <<= 1) {
        int x = (b >= off) ? t[b - off] : 0;
        __syncthreads();
        t[b] += x;
        __syncthreads();
    }
    bstart[b] = t[b] - v;
    if (b == NBUCK - 1) {
        bstart[NBUCK] = t[b];
        slotstart[MAX_SLOTS] = t[b];
    }
}

__device__ __forceinline__ void scat1(int d, int s, const int* __restrict__ slot,
                                      int* cur, int* __restrict__ bins) {
    int r = slot[d];
    if (r) {
        int sl = r - 1;
        int pos = atomicAdd(&cur[sl >> BSH], 1);
        bins[pos] = ((sl & 127) << 17) | s;
    }
}

// Deterministic bucket scatter: LDS cursors seeded from bstart + bpart prefix.
__global__ void k_bscatter(const int* __restrict__ src, const int* __restrict__ dst,
                           const int* __restrict__ slot, const int* __restrict__ bpart,
                           const int* __restrict__ bstart, int* __restrict__ bins) {
    __shared__ int cur[NBUCK];
    int g = blockIdx.x;
    if (threadIdx.x < NBUCK)
        cur[threadIdx.x] = bstart[threadIdx.x] + bpart[threadIdx.x * SLICES + g];
    __syncthreads();
    const int4* d4 = (const int4*)(dst + g * EPS2);
    const int4* s4 = (const int4*)(src + g * EPS2);
    for (int i = threadIdx.x; i < I4PS2; i += 512) {
        int4 d = d4[i];
        int4 s = s4[i];
        scat1(d.x, s.x, slot, cur, bins);
        scat1(d.y, s.y, slot, cur, bins);
        scat1(d.z, s.z, slot, cur, bins);
        scat1(d.w, s.w, slot, cur, bins);
    }
}

// Per-bucket counting sort -> per-slot CSR (slotstart, bins2). LDS atomics only.
__global__ void k_bsort(const int* __restrict__ bstart, const int* __restrict__ bins,
                        int* __restrict__ slotstart, int* __restrict__ bins2) {
    __shared__ int lc[128];
    __shared__ int st[128];
    int b = blockIdx.x;
    int tid = threadIdx.x;
    if (tid < 128) lc[tid] = 0;
    __syncthreads();
    int beg = bstart[b], end = bstart[b + 1];
    for (int j = beg + tid; j < end; j += 256)
        atomicAdd(&lc[(bins[j] >> 17) & 127], 1);
    __syncthreads();
    if (tid < 128) st[tid] = lc[tid];
    __syncthreads();
    for (int off = 1; off < 128; off <<= 1) {
        int v = (tid < 128 && tid >= off) ? st[tid - off] : 0;
        __syncthreads();
        if (tid < 128) st[tid] += v;
        __syncthreads();
    }
    if (tid < 128) {
        int s0 = beg + st[tid] - lc[tid];
        slotstart[(b << 7) + tid] = s0;
        lc[tid] = s0;
    }
    __syncthreads();
    for (int j = beg + tid; j < end; j += 256) {
        int e = bins[j];
        int pos = atomicAdd(&lc[(e >> 17) & 127], 1);
        bins2[pos] = e & 0x1FFFF;
    }
}

// One wave per slot, lane = dim; bf16 pre-scaled rows, register accumulation.
__global__ void k_gather(const int* __restrict__ nodelist, const int* __restrict__ slotstart,
                         const int* __restrict__ bins2, const unsigned short* __restrict__ wh,
                         const float* __restrict__ dinv, const float* __restrict__ bias,
                         const int* __restrict__ counters, unsigned short* __restrict__ emb) {
    int s = (blockIdx.x * blockDim.x + threadIdx.x) >> 6;
    int lane = threadIdx.x & 63;
    if (s >= counters[0]) return;
    int n = nodelist[s];
    int beg = slotstart[s];
    int end = slotstart[s + 1];
    float acc = 0.f;
    int j = beg;
    for (; j + 8 <= end; j += 8) {
        int s0 = bins2[j],     s1 = bins2[j + 1], s2 = bins2[j + 2], s3 = bins2[j + 3];
        int s4 = bins2[j + 4], s5 = bins2[j + 5], s6 = bins2[j + 6], s7 = bins2[j + 7];
        float v0 = bfx(wh[(s0 << 6) + lane]);
        float v1 = bfx(wh[(s1 << 6) + lane]);
        float v2 = bfx(wh[(s2 << 6) + lane]);
        float v3 = bfx(wh[(s3 << 6) + lane]);
        float v4 = bfx(wh[(s4 << 6) + lane]);
        float v5 = bfx(wh[(s5 << 6) + lane]);
        float v6 = bfx(wh[(s6 << 6) + lane]);
        float v7 = bfx(wh[(s7 << 6) + lane]);
        acc += v0 + v1 + v2 + v3 + v4 + v5 + v6 + v7;
    }
    for (; j < end; ++j) acc += bfx(wh[(bins2[j] << 6) + lane]);
    float dn = dinv[n];
    float whn = bfx(wh[(n << 6) + lane]);
    emb[(s << 6) + lane] = (unsigned short)bfr((acc + whn) * dn + bias[lane]);
}

// One wave per pair: FM pairwise term == dot(emb_a, emb_b).
__global__ void k_final(const int* __restrict__ pairs, const int* __restrict__ slot,
                        const unsigned short* __restrict__ emb, const float* __restrict__ lw,
                        const float* __restrict__ lb, float* __restrict__ out) {
    int p = (blockIdx.x * blockDim.x + threadIdx.x) >> 6;
    int lane = threadIdx.x & 63;
    if (p >= BATCH) return;
    int a = pairs[p * 2 + 0];
    int b = pairs[p * 2 + 1];
    int sa = slot[a] - 1;
    int sb = slot[b] - 1;
    float ea = bfx(emb[(sa << 6) + lane]);
    float eb = bfx(emb[(sb << 6) + lane]);
    float prod = ea * eb;
#pragma unroll
    for (int m = 32; m >= 1; m >>= 1) prod += __shfl_xor(prod, m, 64);
    if (lane == 0) out[p] = lw[a] + lw[b] + lb[0] + prod;
}

extern "C" void kernel_launch(void* const* d_in, const int* in_sizes, int n_in,
                              void* d_out, int out_size, void* d_ws, size_t ws_size,
                              hipStream_t stream) {
    const float* gcn_weight    = (const float*)d_in[0];
    const float* gcn_bias      = (const float*)d_in[1];
    const float* linear_weight = (const float*)d_in[2];
    const float* linear_bias   = (const float*)d_in[3];
    const int*   edge_index    = (const int*)d_in[4];
    const int*   pairs         = (const int*)d_in[5];
    float* out = (float*)d_out;

    char* ws = (char*)d_ws;
    int*            slot      = (int*)           (ws + OFF_SLOT);
    int*            counters  = (int*)           (ws + OFF_COUNTERS);
    float*          dinv      = (float*)         (ws + OFF_DINV);
    int*            nodelist  = (int*)           (ws + OFF_NODELIST);
    int*            bstart    = (int*)           (ws + OFF_BSTART);
    int*            btot      = (int*)           (ws + OFF_BTOT);
    int*            bpart     = (int*)           (ws + OFF_BPART);
    int*            slotstart = (int*)           (ws + OFF_SLOTSTART);
    unsigned*       partials  = (unsigned*)      (ws + OFF_PARTIALS);
    unsigned*       wh32      = (unsigned*)      (ws + OFF_WH);
    unsigned short* wh        = (unsigned short*)(ws + OFF_WH);
    int*            bins2     = (int*)           (ws + OFF_BINS2);
    int*            bins      = (int*)           (ws + OFF_BINS);
    unsigned short* emb       = (unsigned short*)(ws + OFF_EMB);

    const int* src_arr = edge_index;
    const int* dst_arr = edge_index + N_EDGES;

    k_init<<<98, 256, 0, stream>>>((int4*)(ws + OFF_SLOT), counters);
    k_flags<<<128, 256, 0, stream>>>(pairs, slot);
    k_compact<<<391, 256, 0, stream>>>(slot, nodelist, counters);
    k_hist<<<HP * HG, 512, 0, stream>>>(dst_arr, partials);
    k_dinv<<<196, 256, 0, stream>>>(partials, dinv);      // partials dead after this
    k_cvt<<<12500, 256, 0, stream>>>((const float2*)gcn_weight, dinv, wh32);
    k_bhist<<<SLICES, 512, 0, stream>>>(dst_arr, slot, bpart);
    k_bpfx1<<<NBUCK, 256, 0, stream>>>(bpart, btot);
    k_bpfx2<<<1, 256, 0, stream>>>(btot, bstart, slotstart);
    k_bscatter<<<SLICES, 512, 0, stream>>>(src_arr, dst_arr, slot, bpart, bstart, bins);
    k_bsort<<<NBUCK, 256, 0, stream>>>(bstart, bins, slotstart, bins2);
    k_gather<<<MAX_SLOTS / 4, 256, 0, stream>>>(nodelist, slotstart, bins2, wh,
                                                dinv, gcn_bias, counters, emb);
    k_final<<<BATCH / 4, 256, 0, stream>>>(pairs, slot, emb, linear_weight, linear_bias, out);
}